// Round 1
// baseline (137.369 us; speedup 1.0000x reference)
//
#include <hip/hip_runtime.h>
#include <hip/hip_bf16.h>
#include <stdint.h>

#define B_ROWS 8192
#define DIM 256
#define JCHUNK 512
#define WPB 4   // waves per block
#define ROWS_PER_WAVE 64
#define ROWS_PER_BLOCK (WPB * ROWS_PER_WAVE)  // 256
#define NT (JCHUNK / 16)                      // 32 j-tiles per block
#define NTILES 4                              // A row-tiles per wave

typedef __bf16 bf16x8 __attribute__((ext_vector_type(8)));
typedef float f32x4 __attribute__((ext_vector_type(4)));

#if __has_builtin(__builtin_amdgcn_exp2f)
#define EXP2F(x) __builtin_amdgcn_exp2f(x)
#else
#define EXP2F(x) exp2f(x)
#endif

__device__ __forceinline__ unsigned short f2bf_rne(float f) {
    unsigned int u = __builtin_bit_cast(unsigned int, f);
    unsigned int r = (u + 0x7FFFu + ((u >> 16) & 1u)) >> 16;
    return (unsigned short)r;
}

// ---------------- Kernel 1: L2-normalize rows -> bf16, plus zero accumulators ----------------
__global__ __launch_bounds__(256) void normalize_k(const float* __restrict__ emb,
                                                   unsigned short* __restrict__ ebf,
                                                   float* __restrict__ Sall) {  // 2*8192 floats
    const int idx = blockIdx.x * 256 + threadIdx.x;
    if (idx < 4096) {
        float4 z = {0.f, 0.f, 0.f, 0.f};
        reinterpret_cast<float4*>(Sall)[idx] = z;
    }
    const int row = blockIdx.x * 4 + (threadIdx.x >> 6);
    const int lane = threadIdx.x & 63;  // 4 floats each covers DIM=256
    const float4 v = reinterpret_cast<const float4*>(emb + (size_t)row * DIM)[lane];
    float ss = v.x * v.x + v.y * v.y + v.z * v.z + v.w * v.w;
    #pragma unroll
    for (int off = 32; off; off >>= 1) ss += __shfl_xor(ss, off);
    const float scale = 1.0f / fmaxf(sqrtf(ss), 1e-12f);
    ushort4 o;
    o.x = f2bf_rne(v.x * scale);
    o.y = f2bf_rne(v.y * scale);
    o.z = f2bf_rne(v.z * scale);
    o.w = f2bf_rne(v.w * scale);
    reinterpret_cast<ushort4*>(ebf + (size_t)row * DIM)[lane] = o;
}

// ---------------- Kernel 2: fused sim + masked exp-sum, BARRIER-FREE ----------------
// 64 rows/wave (4 A-tiles register/AGPR-resident, K=256). B fragments are read
// directly from L2 (ebf = 4 MB, fully cache-resident) via a depth-4 register ring
// prefetched 3 k-steps ahead. No LDS staging for B, no per-tile __syncthreads:
// waves stream independently, so MFMA overlaps L2 latency + VALU epilogue freely.
__global__ __launch_bounds__(256, 2) void sim_k(const unsigned short* __restrict__ ebf,
                                                const int* __restrict__ labels,
                                                float* __restrict__ Sall,
                                                float* __restrict__ Spos) {
    // exp((dot-1)/T) = exp2((dot-1) * INV_T*log2e)
    constexpr float K2 = 14.285714285714286f * 1.4426950408889634f;  // 20.60993
    __shared__ int lds_lab[JCHUNK];

    const int tid  = threadIdx.x;
    const int wave = tid >> 6;
    const int lane = tid & 63;
    const int col  = lane & 15;
    const int quad = lane >> 4;

    const int rowblk = blockIdx.x >> 4;            // 0..31
    const int jblk   = blockIdx.x & 15;            // 0..15
    const int i_base = rowblk * ROWS_PER_BLOCK + wave * ROWS_PER_WAVE;
    const int j0     = jblk * JCHUNK;

    // labels for this j-chunk -> LDS (single barrier, before first epilogue use)
    lds_lab[tid] = labels[j0 + tid];
    lds_lab[256 + tid] = labels[j0 + 256 + tid];

    // ---- Preload A-fragments (4 tiles x 8 K-steps) + row labels ----
    // lane L holds A[row = L&15][k = kk*32 + (L>>4)*8 + 0..7]
    bf16x8 afrag[NTILES][8];
    int li[NTILES][4];
    #pragma unroll
    for (int t = 0; t < NTILES; ++t) {
        const int arow = i_base + t * 16 + col;
        const uint4* ap = reinterpret_cast<const uint4*>(ebf) + (size_t)arow * 32 + quad;
        #pragma unroll
        for (int kk = 0; kk < 8; ++kk)
            afrag[t][kk] = __builtin_bit_cast(bf16x8, ap[kk * 4]);
        #pragma unroll
        for (int r = 0; r < 4; ++r)
            li[t][r] = labels[i_base + t * 16 + quad * 4 + r];
    }

    // Per-lane B base: row (j0 + col), bytes quad*16; k-step kk adds kk*64,
    // j-tile jt adds jt*8192 (16 rows * 512 B). Identical fragment layout to the
    // LDS path of the previous version (proven correct).
    const char* gB = reinterpret_cast<const char*>(ebf) + (size_t)(j0 + col) * 512 + quad * 16;

    // Ring warm-up: global k-steps g = 0,1,2 (tile 0, kk = 0..2)
    bf16x8 ring[4];
    ring[0] = *reinterpret_cast<const bf16x8*>(gB + 0 * 64);
    ring[1] = *reinterpret_cast<const bf16x8*>(gB + 1 * 64);
    ring[2] = *reinterpret_cast<const bf16x8*>(gB + 2 * 64);

    __syncthreads();  // lds_lab ready (only barrier in the kernel)

    float s_all[NTILES][4] = {};
    float s_pos[NTILES][4] = {};

    const char* gBt = gB;  // current tile base
    for (int jt = 0; jt < NT; ++jt) {
        // next-tile base; on the last tile wrap to tile 0 (dead loads, in-bounds)
        const char* gBn = (jt + 1 < NT) ? (gBt + 8192) : gB;

        f32x4 acc[NTILES];
        #pragma unroll
        for (int t = 0; t < NTILES; ++t) acc[t] = (f32x4){0.f, 0.f, 0.f, 0.f};

        #pragma unroll
        for (int kk = 0; kk < 8; ++kk) {
            // prefetch global k-step g = jt*8 + kk + 3 into ring slot (kk+3)&3
            if (kk < 5)
                ring[(kk + 3) & 3] = *reinterpret_cast<const bf16x8*>(gBt + (kk + 3) * 64);
            else
                ring[(kk + 3) & 3] = *reinterpret_cast<const bf16x8*>(gBn + (kk - 5) * 64);
            const bf16x8 bfrag = ring[kk & 3];
            #pragma unroll
            for (int t = 0; t < NTILES; ++t)
                acc[t] = __builtin_amdgcn_mfma_f32_16x16x32_bf16(afrag[t][kk], bfrag, acc[t], 0, 0, 0);
        }

        const int jcol = j0 + jt * 16 + col;
        const int lj = lds_lab[jt * 16 + col];

        // Epilogue. D[row = quad*4+r][col]. Diagonal only possible when this 16-col
        // strip overlaps the wave's 64-row strip (wave-uniform branch).
        const int jt16 = j0 + jt * 16;
        const bool diag_possible = (jt16 < i_base + ROWS_PER_WAVE) && (i_base < jt16 + 16);
        if (!diag_possible) {
            #pragma unroll
            for (int t = 0; t < NTILES; ++t) {
                #pragma unroll
                for (int r = 0; r < 4; ++r) {
                    const float ex = EXP2F(fmaf(acc[t][r], K2, -K2));
                    s_all[t][r] += ex;
                    s_pos[t][r] += (lj == li[t][r]) ? ex : 0.0f;
                }
            }
        } else {
            #pragma unroll
            for (int t = 0; t < NTILES; ++t) {
                #pragma unroll
                for (int r = 0; r < 4; ++r) {
                    const int irow = i_base + t * 16 + quad * 4 + r;
                    const float ex = EXP2F(fmaf(acc[t][r], K2, -K2));
                    const bool valid = (jcol != irow);
                    const bool pos = valid && (lj == li[t][r]);
                    s_all[t][r] += valid ? ex : 0.0f;
                    s_pos[t][r] += pos ? ex : 0.0f;
                }
            }
        }

        gBt += 8192;
    }

    // Reduce over the 16 column-lanes within each quad, then one atomic per row.
    #pragma unroll
    for (int t = 0; t < NTILES; ++t) {
        #pragma unroll
        for (int r = 0; r < 4; ++r) {
            float a = s_all[t][r];
            float pp = s_pos[t][r];
            #pragma unroll
            for (int off = 1; off < 16; off <<= 1) {
                a += __shfl_xor(a, off);
                pp += __shfl_xor(pp, off);
            }
            if (col == 0) {
                const int irow = i_base + t * 16 + quad * 4 + r;
                atomicAdd(&Sall[irow], a);
                atomicAdd(&Spos[irow], pp);
            }
        }
    }
}

// ---------------- Kernel 3: per-row loss + mean ----------------
__global__ __launch_bounds__(1024) void finalize_k(const float* __restrict__ Sall,
                                                   const float* __restrict__ Spos,
                                                   float* __restrict__ out) {
    const int tid = threadIdx.x;
    float sum = 0.0f;
    int cnt = 0;
    #pragma unroll
    for (int k = 0; k < B_ROWS / 1024; ++k) {
        const int i = k * 1024 + tid;
        const float sp = Spos[i];
        const float sa = Sall[i];
        if (sp > 0.0f) {
            sum += __logf(__fdividef(sa, sp));  // log(sa)-log(sp); fixed max M cancels
            ++cnt;
        }
    }
    #pragma unroll
    for (int off = 32; off; off >>= 1) {
        sum += __shfl_xor(sum, off);
        cnt += __shfl_xor(cnt, off);
    }
    __shared__ float ssum[16];
    __shared__ int scnt[16];
    const int wave = tid >> 6, lane = tid & 63;
    if (lane == 0) { ssum[wave] = sum; scnt[wave] = cnt; }
    __syncthreads();
    if (tid == 0) {
        float s = 0.0f;
        int c = 0;
        #pragma unroll
        for (int w = 0; w < 16; ++w) { s += ssum[w]; c += scnt[w]; }
        out[0] = (c > 0) ? s / (float)c : 0.0f;
    }
}

extern "C" void kernel_launch(void* const* d_in, const int* in_sizes, int n_in,
                              void* d_out, int out_size, void* d_ws, size_t ws_size,
                              hipStream_t stream) {
    const float* emb   = (const float*)d_in[0];
    const int* labels  = (const int*)d_in[1];
    float* out         = (float*)d_out;

    unsigned short* ebf = (unsigned short*)d_ws;                       // 4 MB bf16 normalized
    float* Sall = (float*)((char*)d_ws + (size_t)B_ROWS * DIM * 2);    // 32 KB
    float* Spos = Sall + B_ROWS;                                       // 32 KB

    normalize_k<<<B_ROWS / 4, 256, 0, stream>>>(emb, ebf, Sall);

    dim3 grid((B_ROWS / ROWS_PER_BLOCK) * (B_ROWS / JCHUNK));          // 32*16 = 512
    sim_k<<<grid, 256, 0, stream>>>(ebf, labels, Sall, Spos);

    finalize_k<<<1, 1024, 0, stream>>>(Sall, Spos, out);
}

// Round 2
// 122.612 us; speedup vs baseline: 1.1204x; 1.1204x over previous
//
#include <hip/hip_runtime.h>
#include <hip/hip_bf16.h>
#include <stdint.h>

#define B_ROWS 8192
#define DIM 256
#define JCHUNK 512
#define WPB 4   // waves per block
#define ROWS_PER_WAVE 32
#define ROWS_PER_BLOCK (WPB * ROWS_PER_WAVE)  // 128
#define NT (JCHUNK / 16)                      // 32 j-tiles per block
#define NTILES 2                              // A row-tiles per wave (32 rows)

typedef __bf16 bf16x8 __attribute__((ext_vector_type(8)));
typedef float f32x4 __attribute__((ext_vector_type(4)));

#if __has_builtin(__builtin_amdgcn_exp2f)
#define EXP2F(x) __builtin_amdgcn_exp2f(x)
#else
#define EXP2F(x) exp2f(x)
#endif

__device__ __forceinline__ unsigned short f2bf_rne(float f) {
    unsigned int u = __builtin_bit_cast(unsigned int, f);
    unsigned int r = (u + 0x7FFFu + ((u >> 16) & 1u)) >> 16;
    return (unsigned short)r;
}

// swizzled LDS tile: 16 rows x 512B; chunk c (16B) of row r at r*512 + ((c^r)&31)*16
__device__ __forceinline__ void stw(unsigned char* buf, int r, int c, uint4 v) {
    *reinterpret_cast<uint4*>(&buf[r * 512 + ((c ^ r) & 31) * 16]) = v;
}

// ---------------- Kernel 1: L2-normalize rows -> bf16, plus zero accumulators ----------------
__global__ __launch_bounds__(256) void normalize_k(const float* __restrict__ emb,
                                                   unsigned short* __restrict__ ebf,
                                                   float* __restrict__ Sall) {  // 2*8192 floats
    const int idx = blockIdx.x * 256 + threadIdx.x;
    if (idx < 4096) {
        float4 z = {0.f, 0.f, 0.f, 0.f};
        reinterpret_cast<float4*>(Sall)[idx] = z;
    }
    const int row = blockIdx.x * 4 + (threadIdx.x >> 6);
    const int lane = threadIdx.x & 63;  // 4 floats each covers DIM=256
    const float4 v = reinterpret_cast<const float4*>(emb + (size_t)row * DIM)[lane];
    float ss = v.x * v.x + v.y * v.y + v.z * v.z + v.w * v.w;
    #pragma unroll
    for (int off = 32; off; off >>= 1) ss += __shfl_xor(ss, off);
    const float scale = 1.0f / fmaxf(sqrtf(ss), 1e-12f);
    ushort4 o;
    o.x = f2bf_rne(v.x * scale);
    o.y = f2bf_rne(v.y * scale);
    o.z = f2bf_rne(v.z * scale);
    o.w = f2bf_rne(v.w * scale);
    reinterpret_cast<ushort4*>(ebf + (size_t)row * DIM)[lane] = o;
}

// ---------------- Kernel 2: fused sim + masked exp-sum ----------------
// 32 rows/wave (2 A-tiles register-resident, K=256) -> per-wave unified register
// footprint ~120 so 4 blocks/CU (16 waves/CU) fit; previous 64-row/wave shape was
// 256 regs/wave and capped at 2 waves/SIMD, leaving both pipes <30% (stall-bound).
// B-tile 16 cols x 512B staged in LDS (double-buffered, XOR swizzle), same-iteration
// register prefetch. Total MFMA/VALU work unchanged; only latency overlap improves.
__global__ __launch_bounds__(256, 4) void sim_k(const unsigned short* __restrict__ ebf,
                                                const int* __restrict__ labels,
                                                float* __restrict__ Sall,
                                                float* __restrict__ Spos) {
    // exp((dot-1)/T) = exp2((dot-1) * INV_T*log2e)
    constexpr float K2 = 14.285714285714286f * 1.4426950408889634f;  // 20.60993
    __shared__ __align__(16) unsigned char lds0[8192];
    __shared__ __align__(16) unsigned char lds1[8192];
    __shared__ int lds_lab[JCHUNK];

    const int tid  = threadIdx.x;
    const int wave = tid >> 6;
    const int lane = tid & 63;
    const int col  = lane & 15;
    const int quad = lane >> 4;

    const int rowblk = blockIdx.x >> 4;            // 0..63
    const int jblk   = blockIdx.x & 15;            // 0..15
    const int i_base = rowblk * ROWS_PER_BLOCK + wave * ROWS_PER_WAVE;
    const int j0     = jblk * JCHUNK;

    // ---- Preload A-fragments (2 tiles x 8 K-steps) + row labels ----
    // lane L holds A[row = L&15][k = kk*32 + (L>>4)*8 + 0..7]
    bf16x8 afrag[NTILES][8];
    int li[NTILES][4];
    #pragma unroll
    for (int t = 0; t < NTILES; ++t) {
        const int arow = i_base + t * 16 + col;
        const uint4* ap = reinterpret_cast<const uint4*>(ebf) + (size_t)arow * 32 + quad;
        #pragma unroll
        for (int kk = 0; kk < 8; ++kk)
            afrag[t][kk] = __builtin_bit_cast(bf16x8, ap[kk * 4]);
        #pragma unroll
        for (int r = 0; r < 4; ++r)
            li[t][r] = labels[i_base + t * 16 + quad * 4 + r];
    }

    const int st_r = tid >> 5;      // 0..7
    const int st_c = tid & 31;
    const uint4* gB = reinterpret_cast<const uint4*>(ebf);

    // ---- Prologue: stage tile 0 into lds0; labels -> LDS ----
    lds_lab[tid] = labels[j0 + tid];
    lds_lab[256 + tid] = labels[j0 + 256 + tid];
    {
        const uint4 v0 = gB[(size_t)(j0 + st_r) * 32 + st_c];
        const uint4 v1 = gB[(size_t)(j0 + 8 + st_r) * 32 + st_c];
        stw(lds0, st_r, st_c, v0);
        stw(lds0, st_r + 8, st_c, v1);
    }
    __syncthreads();

    float s_all[NTILES][4] = {};
    float s_pos[NTILES][4] = {};

    for (int jt = 0; jt < NT; ++jt) {
        unsigned char* ldsR = (jt & 1) ? lds1 : lds0;
        unsigned char* ldsW = (jt & 1) ? lds0 : lds1;

        // issue next tile's global loads (consumed at the bottom of this iter)
        uint4 p0, p1;
        const bool havenext = (jt + 1) < NT;
        if (havenext) {
            const int jn = j0 + (jt + 1) * 16;
            p0 = gB[(size_t)(jn + st_r) * 32 + st_c];
            p1 = gB[(size_t)(jn + 8 + st_r) * 32 + st_c];
        }

        // MFMA: load each B-fragment then feed both row-tiles
        f32x4 acc[NTILES];
        #pragma unroll
        for (int t = 0; t < NTILES; ++t) acc[t] = (f32x4){0.f, 0.f, 0.f, 0.f};
        #pragma unroll
        for (int kk = 0; kk < 8; ++kk) {
            const int c = kk * 4 + quad;
            const bf16x8 bfrag = *reinterpret_cast<const bf16x8*>(
                &ldsR[col * 512 + ((c ^ col) & 31) * 16]);
            #pragma unroll
            for (int t = 0; t < NTILES; ++t)
                acc[t] = __builtin_amdgcn_mfma_f32_16x16x32_bf16(afrag[t][kk], bfrag, acc[t], 0, 0, 0);
        }

        const int jcol = j0 + jt * 16 + col;
        const int lj = lds_lab[jt * 16 + col];

        // Epilogue. D[row = quad*4+r][col]. Diagonal only possible when this 16-col
        // strip overlaps the wave's 32-row strip (wave-uniform branch).
        const int jt16 = j0 + jt * 16;
        const bool diag_possible = (jt16 < i_base + ROWS_PER_WAVE) && (i_base < jt16 + 16);
        if (!diag_possible) {
            #pragma unroll
            for (int t = 0; t < NTILES; ++t) {
                #pragma unroll
                for (int r = 0; r < 4; ++r) {
                    const float ex = EXP2F(fmaf(acc[t][r], K2, -K2));
                    s_all[t][r] += ex;
                    s_pos[t][r] += (lj == li[t][r]) ? ex : 0.0f;
                }
            }
        } else {
            #pragma unroll
            for (int t = 0; t < NTILES; ++t) {
                #pragma unroll
                for (int r = 0; r < 4; ++r) {
                    const int irow = i_base + t * 16 + quad * 4 + r;
                    const float ex = EXP2F(fmaf(acc[t][r], K2, -K2));
                    const bool valid = (jcol != irow);
                    const bool pos = valid && (lj == li[t][r]);
                    s_all[t][r] += valid ? ex : 0.0f;
                    s_pos[t][r] += pos ? ex : 0.0f;
                }
            }
        }

        // write next tile into the other buffer, then barrier
        if (havenext) {
            stw(ldsW, st_r, st_c, p0);
            stw(ldsW, st_r + 8, st_c, p1);
        }
        __syncthreads();
    }

    // Reduce over the 16 column-lanes within each quad, then one atomic per row.
    #pragma unroll
    for (int t = 0; t < NTILES; ++t) {
        #pragma unroll
        for (int r = 0; r < 4; ++r) {
            float a = s_all[t][r];
            float pp = s_pos[t][r];
            #pragma unroll
            for (int off = 1; off < 16; off <<= 1) {
                a += __shfl_xor(a, off);
                pp += __shfl_xor(pp, off);
            }
            if (col == 0) {
                const int irow = i_base + t * 16 + quad * 4 + r;
                atomicAdd(&Sall[irow], a);
                atomicAdd(&Spos[irow], pp);
            }
        }
    }
}

// ---------------- Kernel 3: per-row loss + mean ----------------
__global__ __launch_bounds__(1024) void finalize_k(const float* __restrict__ Sall,
                                                   const float* __restrict__ Spos,
                                                   float* __restrict__ out) {
    const int tid = threadIdx.x;
    float sum = 0.0f;
    int cnt = 0;
    #pragma unroll
    for (int k = 0; k < B_ROWS / 1024; ++k) {
        const int i = k * 1024 + tid;
        const float sp = Spos[i];
        const float sa = Sall[i];
        if (sp > 0.0f) {
            sum += __logf(__fdividef(sa, sp));  // log(sa)-log(sp); fixed max M cancels
            ++cnt;
        }
    }
    #pragma unroll
    for (int off = 32; off; off >>= 1) {
        sum += __shfl_xor(sum, off);
        cnt += __shfl_xor(cnt, off);
    }
    __shared__ float ssum[16];
    __shared__ int scnt[16];
    const int wave = tid >> 6, lane = tid & 63;
    if (lane == 0) { ssum[wave] = sum; scnt[wave] = cnt; }
    __syncthreads();
    if (tid == 0) {
        float s = 0.0f;
        int c = 0;
        #pragma unroll
        for (int w = 0; w < 16; ++w) { s += ssum[w]; c += scnt[w]; }
        out[0] = (c > 0) ? s / (float)c : 0.0f;
    }
}

extern "C" void kernel_launch(void* const* d_in, const int* in_sizes, int n_in,
                              void* d_out, int out_size, void* d_ws, size_t ws_size,
                              hipStream_t stream) {
    const float* emb   = (const float*)d_in[0];
    const int* labels  = (const int*)d_in[1];
    float* out         = (float*)d_out;

    unsigned short* ebf = (unsigned short*)d_ws;                       // 4 MB bf16 normalized
    float* Sall = (float*)((char*)d_ws + (size_t)B_ROWS * DIM * 2);    // 32 KB
    float* Spos = Sall + B_ROWS;                                       // 32 KB

    normalize_k<<<B_ROWS / 4, 256, 0, stream>>>(emb, ebf, Sall);

    dim3 grid((B_ROWS / ROWS_PER_BLOCK) * (B_ROWS / JCHUNK));          // 64*16 = 1024
    sim_k<<<grid, 256, 0, stream>>>(ebf, labels, Sall, Spos);

    finalize_k<<<1, 1024, 0, stream>>>(Sall, Spos, out);
}